// Round 12
// baseline (188.781 us; speedup 1.0000x reference)
//
#include <hip/hip_runtime.h>

#define NB 256
#define NM 128
#define ND 64
#define NH 8

typedef float f32x4 __attribute__((ext_vector_type(4)));
typedef short bf16x8 __attribute__((ext_vector_type(8)));   // 8 bf16 = 4 VGPRs (16x16x32 A/B)
typedef short bf16x4 __attribute__((ext_vector_type(4)));   // 4 bf16 = 2 VGPRs (16x16x16 A/B)
typedef unsigned short ushort_t;

__device__ __forceinline__ ushort_t f2bf(float f) {   // RNE f32->bf16
    unsigned int x = __float_as_uint(f);
    x += 0x7fffu + ((x >> 16) & 1u);
    return (ushort_t)(x >> 16);
}
__device__ __forceinline__ unsigned pk2(float a, float b) {
    return (unsigned)f2bf(a) | ((unsigned)f2bf(b) << 16);
}
__device__ __forceinline__ bf16x4 pk4(float a, float b, float c, float d) {
    bf16x4 t;
    t[0] = (short)f2bf(a); t[1] = (short)f2bf(b);
    t[2] = (short)f2bf(c); t[3] = (short)f2bf(d);
    return t;
}
__device__ __forceinline__ f32x4 vmax4(f32x4 a, f32x4 b) {
    f32x4 r;
#pragma unroll
    for (int i = 0; i < 4; ++i) r[i] = fmaxf(a[i], b[i]);
    return r;
}

// XOR-swizzled LDS indices (T2): col ^= 8*(row&7), write and read. XOR by
// multiples of 8 elements preserves 4-aligned b64 chunks (4g mod 8 in {0,4}).
__device__ __forceinline__ int sw64(int row, int col)  { return row * 64  + (col ^ ((row & 7) << 3)); }
__device__ __forceinline__ int sw128(int row, int col) { return row * 128 + (col ^ ((row & 7) << 3)); }

__device__ __forceinline__ f32x4 MFMA(bf16x8 a, bf16x8 b, f32x4 c) {
    return __builtin_amdgcn_mfma_f32_16x16x32_bf16(a, b, c, 0, 0, 0);
}

// 16x16x16 bf16 MFMA: A/B = 4 bf16/lane (lane(c,g): row/col=c, k=4g+j).
#if defined(__has_builtin)
#if __has_builtin(__builtin_amdgcn_mfma_f32_16x16x16bf16_1k)
#define HAVE_MFMA16 1
__device__ __forceinline__ f32x4 MFMA16(bf16x4 a, bf16x4 b, f32x4 c) {
    return __builtin_amdgcn_mfma_f32_16x16x16bf16_1k(a, b, c, 0, 0, 0);
}
#endif
#endif
#ifndef HAVE_MFMA16
__device__ __forceinline__ f32x4 MFMA16(bf16x4 a, bf16x4 b, f32x4 c) {
    f32x4 d;
    asm volatile("v_mfma_f32_16x16x16_bf16 %0, %1, %2, %3\n\ts_nop 7\n\ts_nop 7"
                 : "=v"(d) : "v"(a), "v"(b), "v"(c));
    return d;
}
#endif

// ---- prep: transpose weights to bf16 fragment layout in d_ws ----
// ws (ushort): WqT[512][64] @0, WkT @32768, WvT @65536, WpT[64][512] @98304 (256 KB)
extern "C" __global__ void geat_prep(const float* __restrict__ Wq,
                                     const float* __restrict__ Wk,
                                     const float* __restrict__ Wv,
                                     const float* __restrict__ Wp,
                                     ushort_t* __restrict__ ws)
{
    int idx = blockIdx.x * 256 + threadIdx.x;   // 0..131071
    int seg = idx >> 15;
    int r = idx & 32767;
    float v;
    if      (seg == 0) v = Wq[(r & 63) * 512 + (r >> 6)];    // WqT[o][d] = Wq[d][o]
    else if (seg == 1) v = Wk[(r & 63) * 512 + (r >> 6)];
    else if (seg == 2) v = Wv[(r & 63) * 512 + (r >> 6)];
    else               v = Wp[(r & 511) * 64 + (r >> 9)];    // WpT[c][k] = Wp[k][c]
    ws[idx] = f2bf(v);
}

// ============================================================================
// Two-team, 1024-thread fused kernel. Grid 256 (1 block/CU), 16 waves = 4/SIMD
// (r6/r10/r11 all sat at 2/SIMD and all landed ~140us: latency-bound; this is
// the occupancy fix that needs NO multi-block co-scheduling).
// Team t (waves 8t..8t+7) runs the r11 pipeline on heads 4t..4t+3 with its own
// double-buffered K/V^T LDS region (64 KB/team, 128 KB total). Wave wl owns
// token rows 16wl..16wl+15; lane (c,g) owns score row mt+c end-to-end:
//   S^T = mfma16(K-gran, Q-gran); softmax in-reg (2 shuffles); PV and oproj
//   straight from granules. Only K and V^T touch LDS.
// Final: team1 stages its projacc partial (32 KB f32), team0 adds + stores.
// DO NOT pass a >1 min-waves hint (r2/r5: VGPR cap = spill disaster).
// ============================================================================
extern "C" __global__ __launch_bounds__(1024, 1)
void geat_pipe(const float* __restrict__ x, const int* __restrict__ edges,
               const float* __restrict__ bq, const float* __restrict__ bk,
               const float* __restrict__ bv, const float* __restrict__ ebias,
               const float* __restrict__ bp, const ushort_t* __restrict__ wt,
               float* __restrict__ out)
{
    __shared__ __align__(16) ushort_t sm[65536];  // 128 KB: team t at +t*32768 (2 buffers x 32 KB)

    const int b    = blockIdx.x;
    const int tid  = threadIdx.x;
    const int w    = tid >> 6;          // wave 0..15
    const int team = w >> 3;            // 0 or 1
    const int wl   = w & 7;             // wave-in-team
    const int lane = tid & 63;
    const int c    = lane & 15;
    const int g    = lane >> 4;
    const int mt   = wl * 16;           // wave's 16 token rows
    ushort_t* tbase = sm + team * 32768;

    const ushort_t* WqT = wt;
    const ushort_t* WkT = wt + 32768;
    const ushort_t* WvT = wt + 65536;
    const ushort_t* WpT = wt + 98304;

    // ---- x frags for own rows (A-frag rows mt+c / B-frag cols mt+c) ----
    bf16x8 xA[2];
    {
        const float* xb = x + (size_t)b * NM * ND + (mt + c) * ND;
#pragma unroll
        for (int kt = 0; kt < 2; ++kt) {
            const float4 lo = *(const float4*)&xb[kt * 32 + 8 * g];
            const float4 hi = *(const float4*)&xb[kt * 32 + 8 * g + 4];
            bf16x8 f;
            f[0] = f2bf(lo.x); f[1] = f2bf(lo.y); f[2] = f2bf(lo.z); f[3] = f2bf(lo.w);
            f[4] = f2bf(hi.x); f[5] = f2bf(hi.y); f[6] = f2bf(hi.z); f[7] = f2bf(hi.w);
            xA[kt] = f;
        }
    }

    // ---- edge codes for row mt+c: n = 16nt+4g+r, packed 4x8b per nt ----
    unsigned epack[8];
    {
        const int* erow = edges + (size_t)b * NM * NM + (mt + c) * NM;
#pragma unroll
        for (int nt = 0; nt < 8; ++nt) {
            const int4 e4 = *(const int4*)&erow[nt * 16 + 4 * g];
            epack[nt] = (unsigned)(e4.x & 0xff) | ((unsigned)(e4.y & 0xff) << 8) |
                        ((unsigned)(e4.z & 0xff) << 16) | ((unsigned)(e4.w & 0xff) << 24);
        }
    }

    f32x4 projacc[4];
#pragma unroll
    for (int i = 0; i < 4; ++i) projacc[i] = (f32x4)0.0f;

    bf16x4 qcur[4], qnext[4];   // Q[mt+c][16kt+4g+j] B-granules

    // PROJ head h2 into buf: K -> KB[token][d] (b64), V^T -> VTB[d][token] (b64),
    // Q -> qout granules (registers only).
    auto PROJ = [&](int h2, ushort_t* buf, bf16x4* qout) {
        ushort_t* KBn = buf;
        ushort_t* VTn = buf + 8192;
#pragma unroll
        for (int dt = 0; dt < 4; ++dt) {
            const int d0 = dt * 16;
            f32x4 qT = (f32x4)0.0f, kT = (f32x4)0.0f, vn = (f32x4)0.0f;
#pragma unroll
            for (int kt = 0; kt < 2; ++kt) {
                const int woff = (h2 * 64 + d0 + c) * 64 + kt * 32 + 8 * g;
                const bf16x8 wq = *(const bf16x8*)&WqT[woff];
                const bf16x8 wk = *(const bf16x8*)&WkT[woff];
                const bf16x8 wv = *(const bf16x8*)&WvT[woff];
                qT = MFMA(wq, xA[kt], qT);   // D: Q[mt+c][d0+4g+r]
                kT = MFMA(wk, xA[kt], kT);   // D: K[mt+c][d0+4g+r]
                vn = MFMA(xA[kt], wv, vn);   // D: V[mt+4g+r][d0+c]
            }
            const float4 bqv = *(const float4*)&bq[h2 * 64 + d0 + 4 * g];
            const float4 bkv = *(const float4*)&bk[h2 * 64 + d0 + 4 * g];
            const float  bvv = bv[h2 * 64 + d0 + c];
            qout[dt] = pk4(qT[0] + bqv.x, qT[1] + bqv.y, qT[2] + bqv.z, qT[3] + bqv.w);
            uint2 kp, vp;
            kp.x = pk2(kT[0] + bkv.x, kT[1] + bkv.y);
            kp.y = pk2(kT[2] + bkv.z, kT[3] + bkv.w);
            vp.x = pk2(vn[0] + bvv, vn[1] + bvv);
            vp.y = pk2(vn[2] + bvv, vn[3] + bvv);
            *(uint2*)&KBn[sw64(mt + c, d0 + 4 * g)] = kp;
            *(uint2*)&VTn[sw128(d0 + c, mt + 4 * g)] = vp;
        }
    };

    // ---- prologue: first team head into buffer 0 ----
    PROJ(team * 4, tbase, qcur);
    __syncthreads();

#pragma unroll 1
    for (int hh = 0; hh < 4; ++hh) {
        const int h = team * 4 + hh;
        ushort_t* bufc = tbase + (hh & 1) * 16384;
        ushort_t* bufn = tbase + ((hh & 1) ^ 1) * 16384;
        ushort_t* KBc  = bufc;
        ushort_t* VTc  = bufc + 8192;

        // pipeline: project next head (weight-load latency hides under attention)
        if (hh < 3) PROJ(h + 1, bufn, qnext);

        const float eb0 = ebias[0 * NH + h], eb1 = ebias[1 * NH + h], eb2 = ebias[2 * NH + h];
        const float eb3 = ebias[3 * NH + h], eb4 = ebias[4 * NH + h];

        // ---- S^T tiles: lane (c,g) gets S[mt+c][16nt+4g+r] ----
        f32x4 s[8];
#pragma unroll
        for (int nt = 0; nt < 8; ++nt) {
            const int n0 = nt * 16;
            f32x4 acc = (f32x4)0.0f;
#pragma unroll
            for (int kt = 0; kt < 4; ++kt) {
                const bf16x4 kgr = *(const bf16x4*)&KBc[sw64(n0 + c, kt * 16 + 4 * g)];
                acc = MFMA16(kgr, qcur[kt], acc);
            }
#pragma unroll
            for (int r = 0; r < 4; ++r) {
                const int e = (epack[nt] >> (8 * r)) & 0xff;
                const float bias = (e == 1) ? eb1 : (e == 2) ? eb2 : (e == 3) ? eb3 : (e == 4) ? eb4 : eb0;
                float sv = acc[r] * 0.125f + bias;
                sv = (sv > 0.f) ? sv : 0.2f * sv;      // leaky BEFORE mask (ref order)
                acc[r] = (e > 0) ? sv : -1e9f;
            }
            s[nt] = acc;
        }

        // ---- softmax over the lane's own row: in-reg tree + 2 shuffles ----
        float mx;
        {
            f32x4 t0 = vmax4(s[0], s[1]), t1 = vmax4(s[2], s[3]);
            f32x4 t2 = vmax4(s[4], s[5]), t3 = vmax4(s[6], s[7]);
            t0 = vmax4(t0, t1); t2 = vmax4(t2, t3); t0 = vmax4(t0, t2);
            mx = fmaxf(fmaxf(t0[0], t0[1]), fmaxf(t0[2], t0[3]));
            mx = fmaxf(mx, __shfl_xor(mx, 16));
            mx = fmaxf(mx, __shfl_xor(mx, 32));
        }
#pragma unroll
        for (int nt = 0; nt < 8; ++nt)
#pragma unroll
            for (int r = 0; r < 4; ++r) s[nt][r] = __expf(s[nt][r] - mx);
        float sum;
        {
            f32x4 t0 = s[0] + s[1], t1 = s[2] + s[3], t2 = s[4] + s[5], t3 = s[6] + s[7];
            t0 = t0 + t1; t2 = t2 + t3; t0 = t0 + t2;
            sum = (t0[0] + t0[1]) + (t0[2] + t0[3]);
            sum += __shfl_xor(sum, 16);
            sum += __shfl_xor(sum, 32);
        }
        const float inv = 1.f / sum;

        // ---- P granules (registers only) ----
        bf16x4 pg[8];
#pragma unroll
        for (int nt = 0; nt < 8; ++nt)
            pg[nt] = pk4(s[nt][0] * inv, s[nt][1] * inv, s[nt][2] * inv, s[nt][3] * inv);

        // ---- O = P·V via mfma16: lane gets O[mt+c][d0+4g+r] ----
        f32x4 ot[4];
#pragma unroll
        for (int dt = 0; dt < 4; ++dt) ot[dt] = (f32x4)0.0f;
#pragma unroll
        for (int dt = 0; dt < 4; ++dt) {
            const int d0 = dt * 16;
#pragma unroll
            for (int nt = 0; nt < 8; ++nt) {
                const bf16x4 vgr = *(const bf16x4*)&VTc[sw128(d0 + c, nt * 16 + 4 * g)];
                ot[dt] = MFMA16(vgr, pg[nt], ot[dt]);
            }
        }

        // ---- out-proj accumulate straight from O granules ----
        bf16x4 ogr[4];
#pragma unroll
        for (int dt = 0; dt < 4; ++dt)
            ogr[dt] = pk4(ot[dt][0], ot[dt][1], ot[dt][2], ot[dt][3]);
#pragma unroll
        for (int nt4 = 0; nt4 < 4; ++nt4) {
            const int n0 = nt4 * 16;
#pragma unroll
            for (int dt = 0; dt < 4; ++dt) {
                const bf16x4 wgr = *(const bf16x4*)&WpT[(n0 + c) * 512 + h * 64 + dt * 16 + 4 * g];
                projacc[nt4] = MFMA16(ogr[dt], wgr, projacc[nt4]);
            }
        }

        __syncthreads();   // one barrier per head: bufn ready, bufc free
        if (hh < 3) {
#pragma unroll
            for (int dt = 0; dt < 4; ++dt) qcur[dt] = qnext[dt];
        }
    }

    // ---- cross-team reduce: team1 stages partial (32 KB f32), team0 adds + stores ----
    float* redf = (float*)sm;   // all LDS free after the final barrier
    if (team == 1) {
#pragma unroll
        for (int nt4 = 0; nt4 < 4; ++nt4)
#pragma unroll
            for (int r = 0; r < 4; ++r)
                redf[(mt + 4 * g + r) * 64 + nt4 * 16 + c] = projacc[nt4][r];
    }
    __syncthreads();
    if (team == 0) {
        float* og = out + (size_t)b * NM * ND;
#pragma unroll
        for (int nt4 = 0; nt4 < 4; ++nt4) {
            const int n0 = nt4 * 16;
            const float bpv = bp[n0 + c];
#pragma unroll
            for (int r = 0; r < 4; ++r)
                og[(mt + 4 * g + r) * ND + n0 + c] =
                    projacc[nt4][r] + redf[(mt + 4 * g + r) * 64 + n0 + c] + bpv;
        }
    }
}

extern "C" void kernel_launch(void* const* d_in, const int* in_sizes, int n_in,
                              void* d_out, int out_size, void* d_ws, size_t ws_size,
                              hipStream_t stream) {
    const float* x     = (const float*)d_in[0];
    const int*   edges = (const int*)d_in[1];
    const float* Wq    = (const float*)d_in[2];
    const float* bq    = (const float*)d_in[3];
    const float* Wk    = (const float*)d_in[4];
    const float* bk    = (const float*)d_in[5];
    const float* Wv    = (const float*)d_in[6];
    const float* bv    = (const float*)d_in[7];
    const float* eb    = (const float*)d_in[8];
    const float* Wp    = (const float*)d_in[9];
    const float* bp    = (const float*)d_in[10];
    float* out = (float*)d_out;
    ushort_t* ws = (ushort_t*)d_ws;   // needs 262144 B

    hipLaunchKernelGGL(geat_prep, dim3(512), dim3(256), 0, stream, Wq, Wk, Wv, Wp, ws);
    hipLaunchKernelGGL(geat_pipe, dim3(NB), dim3(1024), 0, stream,
                       x, edges, bq, bk, bv, eb, bp, ws, out);
}

// Round 13
// 147.244 us; speedup vs baseline: 1.2821x; 1.2821x over previous
//
#include <hip/hip_runtime.h>

#define NB 256
#define NM 128
#define ND 64
#define NH 8

typedef float f32x4 __attribute__((ext_vector_type(4)));
typedef short bf16x8 __attribute__((ext_vector_type(8)));   // 8 bf16 = 4 VGPRs (16x16x32 A/B)
typedef short bf16x4 __attribute__((ext_vector_type(4)));   // 4 bf16 = 2 VGPRs (16x16x16 A/B)
typedef unsigned short ushort_t;

__device__ __forceinline__ ushort_t f2bf(float f) {   // RNE f32->bf16
    unsigned int x = __float_as_uint(f);
    x += 0x7fffu + ((x >> 16) & 1u);
    return (ushort_t)(x >> 16);
}
__device__ __forceinline__ unsigned pk2(float a, float b) {
    return (unsigned)f2bf(a) | ((unsigned)f2bf(b) << 16);
}
__device__ __forceinline__ bf16x4 pk4(float a, float b, float c, float d) {
    bf16x4 t;
    t[0] = (short)f2bf(a); t[1] = (short)f2bf(b);
    t[2] = (short)f2bf(c); t[3] = (short)f2bf(d);
    return t;
}
__device__ __forceinline__ f32x4 vmax4(f32x4 a, f32x4 b) {
    f32x4 r;
#pragma unroll
    for (int i = 0; i < 4; ++i) r[i] = fmaxf(a[i], b[i]);
    return r;
}

// XOR-swizzled LDS indices (T2): col ^= 8*(row&7), write and read. XOR by
// multiples of 8 elements preserves 4-aligned b64 chunks (4g mod 8 in {0,4}).
__device__ __forceinline__ int sw64(int row, int col)  { return row * 64  + (col ^ ((row & 7) << 3)); }
__device__ __forceinline__ int sw128(int row, int col) { return row * 128 + (col ^ ((row & 7) << 3)); }

__device__ __forceinline__ f32x4 MFMA(bf16x8 a, bf16x8 b, f32x4 c) {
    return __builtin_amdgcn_mfma_f32_16x16x32_bf16(a, b, c, 0, 0, 0);
}

// 16x16x16 bf16 MFMA: A/B = 4 bf16/lane (lane(c,g): row/col=c, k=4g+j).
#if defined(__has_builtin)
#if __has_builtin(__builtin_amdgcn_mfma_f32_16x16x16bf16_1k)
#define HAVE_MFMA16 1
__device__ __forceinline__ f32x4 MFMA16(bf16x4 a, bf16x4 b, f32x4 c) {
    return __builtin_amdgcn_mfma_f32_16x16x16bf16_1k(a, b, c, 0, 0, 0);
}
#endif
#endif
#ifndef HAVE_MFMA16
__device__ __forceinline__ f32x4 MFMA16(bf16x4 a, bf16x4 b, f32x4 c) {
    f32x4 d;
    asm volatile("v_mfma_f32_16x16x16_bf16 %0, %1, %2, %3\n\ts_nop 7\n\ts_nop 7"
                 : "=v"(d) : "v"(a), "v"(b), "v"(c));
    return d;
}
#endif

// ---- prep: transpose weights to bf16 fragment layout in d_ws ----
// ws (ushort): WqT[512][64] @0, WkT @32768, WvT @65536, WpT[64][512] @98304 (256 KB)
// then (float, byte offset 262144): partial[2][256][128][64] = 16 MB
extern "C" __global__ void geat_prep(const float* __restrict__ Wq,
                                     const float* __restrict__ Wk,
                                     const float* __restrict__ Wv,
                                     const float* __restrict__ Wp,
                                     ushort_t* __restrict__ ws)
{
    int idx = blockIdx.x * 256 + threadIdx.x;   // 0..131071
    int seg = idx >> 15;
    int r = idx & 32767;
    float v;
    if      (seg == 0) v = Wq[(r & 63) * 512 + (r >> 6)];    // WqT[o][d] = Wq[d][o]
    else if (seg == 1) v = Wk[(r & 63) * 512 + (r >> 6)];
    else if (seg == 2) v = Wv[(r & 63) * 512 + (r >> 6)];
    else               v = Wp[(r & 511) * 64 + (r >> 9)];    // WpT[c][k] = Wp[k][c]
    ws[idx] = f2bf(v);
}

// ============================================================================
// Half-heads attention block: grid 512, 512 thr. Block (b = bid&255, t = bid>>8)
// runs the verified r11 all-register pipeline on heads 4t..4t+3 and writes its
// f32 partial out-projection to pbuf[t]. bid mapping keeps both blocks of a
// molecule on ONE XCD (bid % 8 == b % 8) -> shared x/edges stay L2-hot.
// Rationale (r12): VGPR budget = 65536/block_threads, so 4 waves/SIMD with
// >64 VGPRs REQUIRES two 512-thr blocks/CU (2 x 128-cap), not one 1024-thr.
// LDS 64 KB/block -> two fit in 160 KB. DO NOT pass a min-waves hint (r2/r5).
// ============================================================================
extern "C" __global__ __launch_bounds__(512, 1)
void geat_attn4(const float* __restrict__ x, const int* __restrict__ edges,
                const float* __restrict__ bq, const float* __restrict__ bk,
                const float* __restrict__ bv, const float* __restrict__ ebias,
                const ushort_t* __restrict__ wt, float* __restrict__ pbuf)
{
    __shared__ __align__(16) ushort_t sm[32768];  // 64 KB: 2 x {KB 16KB, VTB 16KB}

    const int bid  = blockIdx.x;
    const int b    = bid & 255;     // molecule selects XCD
    const int t    = bid >> 8;      // head-half 0/1
    const int tid  = threadIdx.x;
    const int lane = tid & 63;
    const int c    = lane & 15;
    const int g    = lane >> 4;
    const int mt   = (tid >> 6) * 16;   // wave's 16 token rows

    const ushort_t* WqT = wt;
    const ushort_t* WkT = wt + 32768;
    const ushort_t* WvT = wt + 65536;
    const ushort_t* WpT = wt + 98304;

    // ---- x frags for own rows (A-frag rows mt+c / B-frag cols mt+c) ----
    bf16x8 xA[2];
    {
        const float* xb = x + (size_t)b * NM * ND + (mt + c) * ND;
#pragma unroll
        for (int kt = 0; kt < 2; ++kt) {
            const float4 lo = *(const float4*)&xb[kt * 32 + 8 * g];
            const float4 hi = *(const float4*)&xb[kt * 32 + 8 * g + 4];
            bf16x8 f;
            f[0] = f2bf(lo.x); f[1] = f2bf(lo.y); f[2] = f2bf(lo.z); f[3] = f2bf(lo.w);
            f[4] = f2bf(hi.x); f[5] = f2bf(hi.y); f[6] = f2bf(hi.z); f[7] = f2bf(hi.w);
            xA[kt] = f;
        }
    }

    // ---- edge codes for row mt+c: n = 16nt+4g+r, packed 4x8b per nt ----
    unsigned epack[8];
    {
        const int* erow = edges + (size_t)b * NM * NM + (mt + c) * NM;
#pragma unroll
        for (int nt = 0; nt < 8; ++nt) {
            const int4 e4 = *(const int4*)&erow[nt * 16 + 4 * g];
            epack[nt] = (unsigned)(e4.x & 0xff) | ((unsigned)(e4.y & 0xff) << 8) |
                        ((unsigned)(e4.z & 0xff) << 16) | ((unsigned)(e4.w & 0xff) << 24);
        }
    }

    f32x4 projacc[4];
#pragma unroll
    for (int i = 0; i < 4; ++i) projacc[i] = (f32x4)0.0f;

    bf16x4 qcur[4], qnext[4];   // Q[mt+c][16kt+4g+j] B-granules

    // PROJ head h2 into buf: K -> KB[token][d] (b64), V^T -> VTB[d][token] (b64),
    // Q -> qout granules (registers only).
    auto PROJ = [&](int h2, ushort_t* buf, bf16x4* qout) {
        ushort_t* KBn = buf;
        ushort_t* VTn = buf + 8192;
#pragma unroll
        for (int dt = 0; dt < 4; ++dt) {
            const int d0 = dt * 16;
            f32x4 qT = (f32x4)0.0f, kT = (f32x4)0.0f, vn = (f32x4)0.0f;
#pragma unroll
            for (int kt = 0; kt < 2; ++kt) {
                const int woff = (h2 * 64 + d0 + c) * 64 + kt * 32 + 8 * g;
                const bf16x8 wq = *(const bf16x8*)&WqT[woff];
                const bf16x8 wk = *(const bf16x8*)&WkT[woff];
                const bf16x8 wv = *(const bf16x8*)&WvT[woff];
                qT = MFMA(wq, xA[kt], qT);   // D: Q[mt+c][d0+4g+r]
                kT = MFMA(wk, xA[kt], kT);   // D: K[mt+c][d0+4g+r]
                vn = MFMA(xA[kt], wv, vn);   // D: V[mt+4g+r][d0+c]
            }
            const float4 bqv = *(const float4*)&bq[h2 * 64 + d0 + 4 * g];
            const float4 bkv = *(const float4*)&bk[h2 * 64 + d0 + 4 * g];
            const float  bvv = bv[h2 * 64 + d0 + c];
            qout[dt] = pk4(qT[0] + bqv.x, qT[1] + bqv.y, qT[2] + bqv.z, qT[3] + bqv.w);
            uint2 kp, vp;
            kp.x = pk2(kT[0] + bkv.x, kT[1] + bkv.y);
            kp.y = pk2(kT[2] + bkv.z, kT[3] + bkv.w);
            vp.x = pk2(vn[0] + bvv, vn[1] + bvv);
            vp.y = pk2(vn[2] + bvv, vn[3] + bvv);
            *(uint2*)&KBn[sw64(mt + c, d0 + 4 * g)] = kp;
            *(uint2*)&VTn[sw128(d0 + c, mt + 4 * g)] = vp;
        }
    };

    // ---- prologue: first head of this half into buffer 0 ----
    PROJ(t * 4, sm, qcur);
    __syncthreads();

#pragma unroll 1
    for (int hh = 0; hh < 4; ++hh) {
        const int h = t * 4 + hh;
        ushort_t* bufc = sm + (hh & 1) * 16384;
        ushort_t* bufn = sm + ((hh & 1) ^ 1) * 16384;
        ushort_t* KBc  = bufc;
        ushort_t* VTc  = bufc + 8192;

        // pipeline: project next head (weight-load latency hides under attention)
        if (hh < 3) PROJ(h + 1, bufn, qnext);

        const float eb0 = ebias[0 * NH + h], eb1 = ebias[1 * NH + h], eb2 = ebias[2 * NH + h];
        const float eb3 = ebias[3 * NH + h], eb4 = ebias[4 * NH + h];

        // ---- S^T tiles: lane (c,g) gets S[mt+c][16nt+4g+r] ----
        f32x4 s[8];
#pragma unroll
        for (int nt = 0; nt < 8; ++nt) {
            const int n0 = nt * 16;
            f32x4 acc = (f32x4)0.0f;
#pragma unroll
            for (int kt = 0; kt < 4; ++kt) {
                const bf16x4 kgr = *(const bf16x4*)&KBc[sw64(n0 + c, kt * 16 + 4 * g)];
                acc = MFMA16(kgr, qcur[kt], acc);
            }
#pragma unroll
            for (int r = 0; r < 4; ++r) {
                const int e = (epack[nt] >> (8 * r)) & 0xff;
                const float bias = (e == 1) ? eb1 : (e == 2) ? eb2 : (e == 3) ? eb3 : (e == 4) ? eb4 : eb0;
                float sv = acc[r] * 0.125f + bias;
                sv = (sv > 0.f) ? sv : 0.2f * sv;      // leaky BEFORE mask (ref order)
                acc[r] = (e > 0) ? sv : -1e9f;
            }
            s[nt] = acc;
        }

        // ---- softmax over the lane's own row: in-reg tree + 2 shuffles ----
        float mx;
        {
            f32x4 t0 = vmax4(s[0], s[1]), t1 = vmax4(s[2], s[3]);
            f32x4 t2 = vmax4(s[4], s[5]), t3 = vmax4(s[6], s[7]);
            t0 = vmax4(t0, t1); t2 = vmax4(t2, t3); t0 = vmax4(t0, t2);
            mx = fmaxf(fmaxf(t0[0], t0[1]), fmaxf(t0[2], t0[3]));
            mx = fmaxf(mx, __shfl_xor(mx, 16));
            mx = fmaxf(mx, __shfl_xor(mx, 32));
        }
#pragma unroll
        for (int nt = 0; nt < 8; ++nt)
#pragma unroll
            for (int r = 0; r < 4; ++r) s[nt][r] = __expf(s[nt][r] - mx);
        float sum;
        {
            f32x4 t0 = s[0] + s[1], t1 = s[2] + s[3], t2 = s[4] + s[5], t3 = s[6] + s[7];
            t0 = t0 + t1; t2 = t2 + t3; t0 = t0 + t2;
            sum = (t0[0] + t0[1]) + (t0[2] + t0[3]);
            sum += __shfl_xor(sum, 16);
            sum += __shfl_xor(sum, 32);
        }
        const float inv = 1.f / sum;

        // ---- P granules (registers only) ----
        bf16x4 pg[8];
#pragma unroll
        for (int nt = 0; nt < 8; ++nt)
            pg[nt] = pk4(s[nt][0] * inv, s[nt][1] * inv, s[nt][2] * inv, s[nt][3] * inv);

        // ---- O = P·V via mfma16: lane gets O[mt+c][d0+4g+r] ----
        f32x4 ot[4];
#pragma unroll
        for (int dt = 0; dt < 4; ++dt) ot[dt] = (f32x4)0.0f;
#pragma unroll
        for (int dt = 0; dt < 4; ++dt) {
            const int d0 = dt * 16;
#pragma unroll
            for (int nt = 0; nt < 8; ++nt) {
                const bf16x4 vgr = *(const bf16x4*)&VTc[sw128(d0 + c, nt * 16 + 4 * g)];
                ot[dt] = MFMA16(vgr, pg[nt], ot[dt]);
            }
        }

        // ---- out-proj accumulate straight from O granules ----
        bf16x4 ogr[4];
#pragma unroll
        for (int dt = 0; dt < 4; ++dt)
            ogr[dt] = pk4(ot[dt][0], ot[dt][1], ot[dt][2], ot[dt][3]);
#pragma unroll
        for (int nt4 = 0; nt4 < 4; ++nt4) {
            const int n0 = nt4 * 16;
#pragma unroll
            for (int dt = 0; dt < 4; ++dt) {
                const bf16x4 wgr = *(const bf16x4*)&WpT[(n0 + c) * 512 + h * 64 + dt * 16 + 4 * g];
                projacc[nt4] = MFMA16(ogr[dt], wgr, projacc[nt4]);
            }
        }

        __syncthreads();   // one barrier per head: bufn ready, bufc free
        if (hh < 3) {
#pragma unroll
            for (int dt = 0; dt < 4; ++dt) qcur[dt] = qnext[dt];
        }
    }

    // ---- write f32 partial to pbuf[t][b] ----
    {
        float* pb = pbuf + ((size_t)t * NB + b) * NM * ND;
#pragma unroll
        for (int nt4 = 0; nt4 < 4; ++nt4) {
            const int n0 = nt4 * 16;
#pragma unroll
            for (int r = 0; r < 4; ++r)
                pb[(mt + 4 * g + r) * ND + n0 + c] = projacc[nt4][r];
        }
    }
}

// ============================================================================
// Reduce: out = partial0 + partial1 + bp. Grid 2048 x 256, float4 per thread.
// ============================================================================
extern "C" __global__ __launch_bounds__(256, 1)
void geat_reduce(const float* __restrict__ pbuf, const float* __restrict__ bp,
                 float* __restrict__ out)
{
    const int i4 = blockIdx.x * 256 + threadIdx.x;        // 0..524287 float4s
    const float4 a  = ((const float4*)pbuf)[i4];
    const float4 bb = ((const float4*)(pbuf + (size_t)NB * NM * ND))[i4];
    const float4 bpv = ((const float4*)bp)[i4 & 15];      // 64 f32 = 16 float4 per row
    float4 o;
    o.x = a.x + bb.x + bpv.x;
    o.y = a.y + bb.y + bpv.y;
    o.z = a.z + bb.z + bpv.z;
    o.w = a.w + bb.w + bpv.w;
    ((float4*)out)[i4] = o;
}

// ============================================================================
// Fallback (r11 fused all-heads, proven 142us): used only if ws too small.
// ============================================================================
extern "C" __global__ __launch_bounds__(512, 1)
void geat_pipe(const float* __restrict__ x, const int* __restrict__ edges,
               const float* __restrict__ bq, const float* __restrict__ bk,
               const float* __restrict__ bv, const float* __restrict__ ebias,
               const float* __restrict__ bp, const ushort_t* __restrict__ wt,
               float* __restrict__ out)
{
    __shared__ __align__(16) ushort_t sm[32768];
    const int b    = blockIdx.x;
    const int tid  = threadIdx.x;
    const int lane = tid & 63;
    const int c    = lane & 15;
    const int g    = lane >> 4;
    const int mt   = (tid >> 6) * 16;

    const ushort_t* WqT = wt;
    const ushort_t* WkT = wt + 32768;
    const ushort_t* WvT = wt + 65536;
    const ushort_t* WpT = wt + 98304;

    bf16x8 xA[2];
    {
        const float* xb = x + (size_t)b * NM * ND + (mt + c) * ND;
#pragma unroll
        for (int kt = 0; kt < 2; ++kt) {
            const float4 lo = *(const float4*)&xb[kt * 32 + 8 * g];
            const float4 hi = *(const float4*)&xb[kt * 32 + 8 * g + 4];
            bf16x8 f;
            f[0] = f2bf(lo.x); f[1] = f2bf(lo.y); f[2] = f2bf(lo.z); f[3] = f2bf(lo.w);
            f[4] = f2bf(hi.x); f[5] = f2bf(hi.y); f[6] = f2bf(hi.z); f[7] = f2bf(hi.w);
            xA[kt] = f;
        }
    }
    unsigned epack[8];
    {
        const int* erow = edges + (size_t)b * NM * NM + (mt + c) * NM;
#pragma unroll
        for (int nt = 0; nt < 8; ++nt) {
            const int4 e4 = *(const int4*)&erow[nt * 16 + 4 * g];
            epack[nt] = (unsigned)(e4.x & 0xff) | ((unsigned)(e4.y & 0xff) << 8) |
                        ((unsigned)(e4.z & 0xff) << 16) | ((unsigned)(e4.w & 0xff) << 24);
        }
    }
    f32x4 projacc[4];
#pragma unroll
    for (int i = 0; i < 4; ++i) projacc[i] = (f32x4)0.0f;
    bf16x4 qcur[4], qnext[4];

    auto PROJ = [&](int h2, ushort_t* buf, bf16x4* qout) {
        ushort_t* KBn = buf;
        ushort_t* VTn = buf + 8192;
#pragma unroll
        for (int dt = 0; dt < 4; ++dt) {
            const int d0 = dt * 16;
            f32x4 qT = (f32x4)0.0f, kT = (f32x4)0.0f, vn = (f32x4)0.0f;
#pragma unroll
            for (int kt = 0; kt < 2; ++kt) {
                const int woff = (h2 * 64 + d0 + c) * 64 + kt * 32 + 8 * g;
                const bf16x8 wq = *(const bf16x8*)&WqT[woff];
                const bf16x8 wk = *(const bf16x8*)&WkT[woff];
                const bf16x8 wv = *(const bf16x8*)&WvT[woff];
                qT = MFMA(wq, xA[kt], qT);
                kT = MFMA(wk, xA[kt], kT);
                vn = MFMA(xA[kt], wv, vn);
            }
            const float4 bqv = *(const float4*)&bq[h2 * 64 + d0 + 4 * g];
            const float4 bkv = *(const float4*)&bk[h2 * 64 + d0 + 4 * g];
            const float  bvv = bv[h2 * 64 + d0 + c];
            qout[dt] = pk4(qT[0] + bqv.x, qT[1] + bqv.y, qT[2] + bqv.z, qT[3] + bqv.w);
            uint2 kp, vp;
            kp.x = pk2(kT[0] + bkv.x, kT[1] + bkv.y);
            kp.y = pk2(kT[2] + bkv.z, kT[3] + bkv.w);
            vp.x = pk2(vn[0] + bvv, vn[1] + bvv);
            vp.y = pk2(vn[2] + bvv, vn[3] + bvv);
            *(uint2*)&KBn[sw64(mt + c, d0 + 4 * g)] = kp;
            *(uint2*)&VTn[sw128(d0 + c, mt + 4 * g)] = vp;
        }
    };

    PROJ(0, sm, qcur);
    __syncthreads();

#pragma unroll 1
    for (int h = 0; h < NH; ++h) {
        ushort_t* bufc = sm + (h & 1) * 16384;
        ushort_t* bufn = sm + ((h & 1) ^ 1) * 16384;
        ushort_t* KBc  = bufc;
        ushort_t* VTc  = bufc + 8192;
        if (h < NH - 1) PROJ(h + 1, bufn, qnext);

        const float eb0 = ebias[0 * NH + h], eb1 = ebias[1 * NH + h], eb2 = ebias[2 * NH + h];
        const float eb3 = ebias[3 * NH + h], eb4 = ebias[4 * NH + h];
        f32x4 s[8];
#pragma unroll
        for (int nt = 0; nt < 8; ++nt) {
            const int n0 = nt * 16;
            f32x4 acc = (f32x4)0.0f;
#pragma unroll
            for (int kt = 0; kt < 4; ++kt) {
                const bf16x4 kgr = *(const bf16x4*)&KBc[sw64(n0 + c, kt * 16 + 4 * g)];
                acc = MFMA16(kgr, qcur[kt], acc);
            }
#pragma unroll
            for (int r = 0; r < 4; ++r) {
                const int e = (epack[nt] >> (8 * r)) & 0xff;
                const float bias = (e == 1) ? eb1 : (e == 2) ? eb2 : (e == 3) ? eb3 : (e == 4) ? eb4 : eb0;
                float sv = acc[r] * 0.125f + bias;
                sv = (sv > 0.f) ? sv : 0.2f * sv;
                acc[r] = (e > 0) ? sv : -1e9f;
            }
            s[nt] = acc;
        }
        float mx;
        {
            f32x4 t0 = vmax4(s[0], s[1]), t1 = vmax4(s[2], s[3]);
            f32x4 t2 = vmax4(s[4], s[5]), t3 = vmax4(s[6], s[7]);
            t0 = vmax4(t0, t1); t2 = vmax4(t2, t3); t0 = vmax4(t0, t2);
            mx = fmaxf(fmaxf(t0[0], t0[1]), fmaxf(t0[2], t0[3]));
            mx = fmaxf(mx, __shfl_xor(mx, 16));
            mx = fmaxf(mx, __shfl_xor(mx, 32));
        }
#pragma unroll
        for (int nt = 0; nt < 8; ++nt)
#pragma unroll
            for (int r = 0; r < 4; ++r) s[nt][r] = __expf(s[nt][r] - mx);
        float sum;
        {
            f32x4 t0 = s[0] + s[1], t1 = s[2] + s[3], t2 = s[4] + s[5], t3 = s[6] + s[7];
            t0 = t0 + t1; t2 = t2 + t3; t0 = t0 + t2;
            sum = (t0[0] + t0[1]) + (t0[2] + t0[3]);
            sum += __shfl_xor(sum, 16);
            sum += __shfl_xor(sum, 32);
        }
        const float inv = 1.f / sum;
        bf16x4 pg[8];
#pragma unroll
        for (int nt = 0; nt < 8; ++nt)
            pg[nt] = pk4(s[nt][0] * inv, s[nt][1] * inv, s[nt][2] * inv, s[nt][3] * inv);
        f32x4 ot[4];
#pragma unroll
        for (int dt = 0; dt < 4; ++dt) ot[dt] = (f32x4)0.0f;
#pragma unroll
        for (int dt = 0; dt < 4; ++dt) {
            const int d0 = dt * 16;
#pragma unroll
            for (int nt = 0; nt < 8; ++nt) {
                const bf16x4 vgr = *(const bf16x4*)&VTc[sw128(d0 + c, nt * 16 + 4 * g)];
                ot[dt] = MFMA16(vgr, pg[nt], ot[dt]);
            }
        }
        bf16x4 ogr[4];
#pragma unroll
        for (int dt = 0; dt < 4; ++dt)
            ogr[dt] = pk4(ot[dt][0], ot[dt][1], ot[dt][2], ot[dt][3]);
#pragma unroll
        for (int nt4 = 0; nt4 < 4; ++nt4) {
            const int n0 = nt4 * 16;
#pragma unroll
            for (int dt = 0; dt < 4; ++dt) {
                const bf16x4 wgr = *(const bf16x4*)&WpT[(n0 + c) * 512 + h * 64 + dt * 16 + 4 * g];
                projacc[nt4] = MFMA16(ogr[dt], wgr, projacc[nt4]);
            }
        }
        __syncthreads();
        if (h < NH - 1) {
#pragma unroll
            for (int dt = 0; dt < 4; ++dt) qcur[dt] = qnext[dt];
        }
    }
    {
        float* og = out + (size_t)b * NM * ND;
#pragma unroll
        for (int nt4 = 0; nt4 < 4; ++nt4) {
            const int n0 = nt4 * 16;
            const float bpv = bp[n0 + c];
#pragma unroll
            for (int r = 0; r < 4; ++r)
                og[(mt + 4 * g + r) * ND + n0 + c] = projacc[nt4][r] + bpv;
        }
    }
}

extern "C" void kernel_launch(void* const* d_in, const int* in_sizes, int n_in,
                              void* d_out, int out_size, void* d_ws, size_t ws_size,
                              hipStream_t stream) {
    const float* x     = (const float*)d_in[0];
    const int*   edges = (const int*)d_in[1];
    const float* Wq    = (const float*)d_in[2];
    const float* bq    = (const float*)d_in[3];
    const float* Wk    = (const float*)d_in[4];
    const float* bk    = (const float*)d_in[5];
    const float* Wv    = (const float*)d_in[6];
    const float* bv    = (const float*)d_in[7];
    const float* eb    = (const float*)d_in[8];
    const float* Wp    = (const float*)d_in[9];
    const float* bp    = (const float*)d_in[10];
    float* out = (float*)d_out;
    ushort_t* ws = (ushort_t*)d_ws;

    hipLaunchKernelGGL(geat_prep, dim3(512), dim3(256), 0, stream, Wq, Wk, Wv, Wp, ws);

    const size_t need = 262144u + 2u * (size_t)NB * NM * ND * sizeof(float);  // 17 MB
    if (ws_size >= need) {
        float* pbuf = (float*)((char*)d_ws + 262144);
        hipLaunchKernelGGL(geat_attn4, dim3(512), dim3(512), 0, stream,
                           x, edges, bq, bk, bv, eb, ws, pbuf);
        hipLaunchKernelGGL(geat_reduce, dim3(2048), dim3(256), 0, stream,
                           pbuf, bp, out);
    } else {
        hipLaunchKernelGGL(geat_pipe, dim3(NB), dim3(512), 0, stream,
                           x, edges, bq, bk, bv, eb, bp, ws, out);
    }
}

// Round 14
// 131.077 us; speedup vs baseline: 1.4402x; 1.1233x over previous
//
#include <hip/hip_runtime.h>

#define NB 256
#define NM 128
#define ND 64
#define NH 8

typedef float f32x4 __attribute__((ext_vector_type(4)));
typedef short bf16x8 __attribute__((ext_vector_type(8)));   // 8 bf16 = 4 VGPRs (16x16x32 A/B)
typedef short bf16x4 __attribute__((ext_vector_type(4)));   // 4 bf16 = 2 VGPRs (16x16x16 A/B)
typedef unsigned short ushort_t;

__device__ __forceinline__ ushort_t f2bf(float f) {   // RNE f32->bf16
    unsigned int x = __float_as_uint(f);
    x += 0x7fffu + ((x >> 16) & 1u);
    return (ushort_t)(x >> 16);
}
__device__ __forceinline__ unsigned pk2(float a, float b) {
    return (unsigned)f2bf(a) | ((unsigned)f2bf(b) << 16);
}
__device__ __forceinline__ bf16x4 pk4(float a, float b, float c, float d) {
    bf16x4 t;
    t[0] = (short)f2bf(a); t[1] = (short)f2bf(b);
    t[2] = (short)f2bf(c); t[3] = (short)f2bf(d);
    return t;
}
__device__ __forceinline__ f32x4 vmax4(f32x4 a, f32x4 b) {
    f32x4 r;
#pragma unroll
    for (int i = 0; i < 4; ++i) r[i] = fmaxf(a[i], b[i]);
    return r;
}

// XOR-swizzled LDS indices (T2): col ^= 8*(row&7), write and read. XOR by
// multiples of 8 elements preserves 4-aligned b64 chunks (4g mod 8 in {0,4}).
__device__ __forceinline__ int sw64(int row, int col)  { return row * 64  + (col ^ ((row & 7) << 3)); }
__device__ __forceinline__ int sw128(int row, int col) { return row * 128 + (col ^ ((row & 7) << 3)); }

__device__ __forceinline__ f32x4 MFMA(bf16x8 a, bf16x8 b, f32x4 c) {
    return __builtin_amdgcn_mfma_f32_16x16x32_bf16(a, b, c, 0, 0, 0);
}

// 16x16x16 bf16 MFMA: A/B = 4 bf16/lane (lane(c,g): row/col=c, k=4g+j).
#if defined(__has_builtin)
#if __has_builtin(__builtin_amdgcn_mfma_f32_16x16x16bf16_1k)
#define HAVE_MFMA16 1
__device__ __forceinline__ f32x4 MFMA16(bf16x4 a, bf16x4 b, f32x4 c) {
    return __builtin_amdgcn_mfma_f32_16x16x16bf16_1k(a, b, c, 0, 0, 0);
}
#endif
#endif
#ifndef HAVE_MFMA16
__device__ __forceinline__ f32x4 MFMA16(bf16x4 a, bf16x4 b, f32x4 c) {
    f32x4 d;
    asm volatile("v_mfma_f32_16x16x16_bf16 %0, %1, %2, %3\n\ts_nop 7\n\ts_nop 7"
                 : "=v"(d) : "v"(a), "v"(b), "v"(c));
    return d;
}
#endif

// ---- prep: transpose weights to bf16 fragment layout in d_ws ----
// ws (ushort): WqT[512][64] @0, WkT @32768, WvT @65536, WpT[64][512] @98304 (256 KB)
extern "C" __global__ void geat_prep(const float* __restrict__ Wq,
                                     const float* __restrict__ Wk,
                                     const float* __restrict__ Wv,
                                     const float* __restrict__ Wp,
                                     ushort_t* __restrict__ ws)
{
    int idx = blockIdx.x * 256 + threadIdx.x;   // 0..131071
    int seg = idx >> 15;
    int r = idx & 32767;
    float v;
    if      (seg == 0) v = Wq[(r & 63) * 512 + (r >> 6)];    // WqT[o][d] = Wq[d][o]
    else if (seg == 1) v = Wk[(r & 63) * 512 + (r >> 6)];
    else if (seg == 2) v = Wv[(r & 63) * 512 + (r >> 6)];
    else               v = Wp[(r & 511) * 64 + (r >> 9)];    // WpT[c][k] = Wp[k][c]
    ws[idx] = f2bf(v);
}

// ============================================================================
// Producer/consumer fused kernel. Grid 256 (1 block/CU), 768 thr = 12 waves =
// 3/SIMD GUARANTEED resident (r13: two blocks never co-schedule on a CU in this
// environment; r12: one big block DOES reach 16 waves but the VGPR law budget =
// 65536/block_threads forces 64 regs -> spill. 768 thr -> ~85-reg budget).
//  - waves 0..7  (consumers): 16 token rows each. Per head: reload x row, Q-proj
//    (8 MFMA32), swapped-S via MFMA16 granules, in-reg softmax (2 shuffles),
//    PV + oproj from granules (r11-verified math). Live set ~75 regs.
//  - waves 8..11 (producers): 32 token rows each. While consumers attend head h,
//    produce K / V^T of head h+1 into the other LDS buffer (role-split: producer
//    VMEM overlaps consumer MFMA on each SIMD).
// LDS 64 KB (2 x {K 16KB, V^T 16KB}); ONE barrier per head, uniform control flow.
// DO NOT pass a >1 min-waves hint (r2/r5: compiler caps VGPRs at 256/min_waves).
// ============================================================================
extern "C" __global__ __launch_bounds__(768, 1)
void geat_pc(const float* __restrict__ x, const int* __restrict__ edges,
             const float* __restrict__ bq, const float* __restrict__ bk,
             const float* __restrict__ bv, const float* __restrict__ ebias,
             const float* __restrict__ bp, const ushort_t* __restrict__ wt,
             float* __restrict__ out)
{
    __shared__ __align__(16) ushort_t sm[32768];  // 64 KB: 2 x {KB 8192, VTB 8192} ushorts

    const int b    = blockIdx.x;
    const int tid  = threadIdx.x;
    const int w    = tid >> 6;          // wave 0..11
    const int lane = tid & 63;
    const int c    = lane & 15;
    const int g    = lane >> 4;
    const bool cons = (w < 8);
    const int mt   = cons ? (w * 16) : ((w - 8) * 32);   // consumer rows / producer base

    const ushort_t* WqT = wt;
    const ushort_t* WkT = wt + 32768;
    const ushort_t* WvT = wt + 65536;
    const ushort_t* WpT = wt + 98304;

    // ---- persistent per-role state ----
    unsigned epack[8];     // consumers: edge codes for row mt+c (n = 16nt+4g+r)
    bf16x8   pxA[2][2];    // producers: x frags for rows mt+16*tile+c
    if (cons) {
        const int* erow = edges + (size_t)b * NM * NM + (mt + c) * NM;
#pragma unroll
        for (int nt = 0; nt < 8; ++nt) {
            const int4 e4 = *(const int4*)&erow[nt * 16 + 4 * g];
            epack[nt] = (unsigned)(e4.x & 0xff) | ((unsigned)(e4.y & 0xff) << 8) |
                        ((unsigned)(e4.z & 0xff) << 16) | ((unsigned)(e4.w & 0xff) << 24);
        }
    } else {
#pragma unroll
        for (int tile = 0; tile < 2; ++tile) {
            const float* xb = x + (size_t)b * NM * ND + (mt + tile * 16 + c) * ND;
#pragma unroll
            for (int kt = 0; kt < 2; ++kt) {
                const float4 lo = *(const float4*)&xb[kt * 32 + 8 * g];
                const float4 hi = *(const float4*)&xb[kt * 32 + 8 * g + 4];
                bf16x8 f;
                f[0] = f2bf(lo.x); f[1] = f2bf(lo.y); f[2] = f2bf(lo.z); f[3] = f2bf(lo.w);
                f[4] = f2bf(hi.x); f[5] = f2bf(hi.y); f[6] = f2bf(hi.z); f[7] = f2bf(hi.w);
                pxA[tile][kt] = f;
            }
        }
    }

    f32x4 projacc[4];
#pragma unroll
    for (int i = 0; i < 4; ++i) projacc[i] = (f32x4)0.0f;

    // ---- producer: K + V^T of head h2 into buf (32 rows: 2 tiles) ----
    auto PROJKV = [&](int h2, ushort_t* buf) {
        ushort_t* KBn = buf;
        ushort_t* VTn = buf + 8192;
#pragma unroll
        for (int dt = 0; dt < 4; ++dt) {
            const int d0 = dt * 16;
            bf16x8 wkf[2], wvf[2];
#pragma unroll
            for (int kt = 0; kt < 2; ++kt) {
                const int woff = (h2 * 64 + d0 + c) * 64 + kt * 32 + 8 * g;
                wkf[kt] = *(const bf16x8*)&WkT[woff];
                wvf[kt] = *(const bf16x8*)&WvT[woff];
            }
            const float4 bkv = *(const float4*)&bk[h2 * 64 + d0 + 4 * g];
            const float  bvv = bv[h2 * 64 + d0 + c];
#pragma unroll
            for (int tile = 0; tile < 2; ++tile) {
                f32x4 kT = (f32x4)0.0f, vn = (f32x4)0.0f;
#pragma unroll
                for (int kt = 0; kt < 2; ++kt) {
                    kT = MFMA(wkf[kt], pxA[tile][kt], kT);   // D: K[row+c][d0+4g+r]
                    vn = MFMA(pxA[tile][kt], wvf[kt], vn);   // D: V[row+4g+r][d0+c]
                }
                const int rowb = mt + tile * 16;
                uint2 kp, vp;
                kp.x = pk2(kT[0] + bkv.x, kT[1] + bkv.y);
                kp.y = pk2(kT[2] + bkv.z, kT[3] + bkv.w);
                vp.x = pk2(vn[0] + bvv, vn[1] + bvv);
                vp.y = pk2(vn[2] + bvv, vn[3] + bvv);
                *(uint2*)&KBn[sw64(rowb + c, d0 + 4 * g)] = kp;
                *(uint2*)&VTn[sw128(d0 + c, rowb + 4 * g)] = vp;
            }
        }
    };

    // ---- prologue: producers fill buffer 0 with head 0's K/V^T ----
    if (!cons) PROJKV(0, sm);
    __syncthreads();

#pragma unroll 1
    for (int h = 0; h < NH; ++h) {
        ushort_t* bufc = sm + (h & 1) * 16384;
        ushort_t* bufn = sm + ((h & 1) ^ 1) * 16384;

        if (cons) {
            ushort_t* KBc = bufc;
            ushort_t* VTc = bufc + 8192;

            // ---- per-head Q-projection (x reloaded from L2; transient regs) ----
            bf16x8 xA[2];
            {
                const float* xb = x + (size_t)b * NM * ND + (mt + c) * ND;
#pragma unroll
                for (int kt = 0; kt < 2; ++kt) {
                    const float4 lo = *(const float4*)&xb[kt * 32 + 8 * g];
                    const float4 hi = *(const float4*)&xb[kt * 32 + 8 * g + 4];
                    bf16x8 f;
                    f[0] = f2bf(lo.x); f[1] = f2bf(lo.y); f[2] = f2bf(lo.z); f[3] = f2bf(lo.w);
                    f[4] = f2bf(hi.x); f[5] = f2bf(hi.y); f[6] = f2bf(hi.z); f[7] = f2bf(hi.w);
                    xA[kt] = f;
                }
            }
            bf16x4 qcur[4];   // Q[mt+c][16dt+4g+j] B-granules
#pragma unroll
            for (int dt = 0; dt < 4; ++dt) {
                const int d0 = dt * 16;
                f32x4 qT = (f32x4)0.0f;
#pragma unroll
                for (int kt = 0; kt < 2; ++kt) {
                    const bf16x8 wq = *(const bf16x8*)&WqT[(h * 64 + d0 + c) * 64 + kt * 32 + 8 * g];
                    qT = MFMA(wq, xA[kt], qT);   // D: Q[mt+c][d0+4g+r]
                }
                const float4 bqv = *(const float4*)&bq[h * 64 + d0 + 4 * g];
                qcur[dt] = pk4(qT[0] + bqv.x, qT[1] + bqv.y, qT[2] + bqv.z, qT[3] + bqv.w);
            }

            const float eb0 = ebias[0 * NH + h], eb1 = ebias[1 * NH + h], eb2 = ebias[2 * NH + h];
            const float eb3 = ebias[3 * NH + h], eb4 = ebias[4 * NH + h];

            // ---- S^T tiles: lane (c,g) gets S[mt+c][16nt+4g+r] ----
            f32x4 s[8];
#pragma unroll
            for (int nt = 0; nt < 8; ++nt) {
                const int n0 = nt * 16;
                f32x4 acc = (f32x4)0.0f;
#pragma unroll
                for (int kt = 0; kt < 4; ++kt) {
                    const bf16x4 kgr = *(const bf16x4*)&KBc[sw64(n0 + c, kt * 16 + 4 * g)];
                    acc = MFMA16(kgr, qcur[kt], acc);
                }
#pragma unroll
                for (int r = 0; r < 4; ++r) {
                    const int e = (epack[nt] >> (8 * r)) & 0xff;
                    const float bias = (e == 1) ? eb1 : (e == 2) ? eb2 : (e == 3) ? eb3 : (e == 4) ? eb4 : eb0;
                    float sv = acc[r] * 0.125f + bias;
                    sv = (sv > 0.f) ? sv : 0.2f * sv;      // leaky BEFORE mask (ref order)
                    acc[r] = (e > 0) ? sv : -1e9f;
                }
                s[nt] = acc;
            }

            // ---- softmax over the lane's own row: in-reg tree + 2 shuffles ----
            float mx;
            {
                f32x4 t0 = vmax4(s[0], s[1]), t1 = vmax4(s[2], s[3]);
                f32x4 t2 = vmax4(s[4], s[5]), t3 = vmax4(s[6], s[7]);
                t0 = vmax4(t0, t1); t2 = vmax4(t2, t3); t0 = vmax4(t0, t2);
                mx = fmaxf(fmaxf(t0[0], t0[1]), fmaxf(t0[2], t0[3]));
                mx = fmaxf(mx, __shfl_xor(mx, 16));
                mx = fmaxf(mx, __shfl_xor(mx, 32));
            }
#pragma unroll
            for (int nt = 0; nt < 8; ++nt)
#pragma unroll
                for (int r = 0; r < 4; ++r) s[nt][r] = __expf(s[nt][r] - mx);
            float sum;
            {
                f32x4 t0 = s[0] + s[1], t1 = s[2] + s[3], t2 = s[4] + s[5], t3 = s[6] + s[7];
                t0 = t0 + t1; t2 = t2 + t3; t0 = t0 + t2;
                sum = (t0[0] + t0[1]) + (t0[2] + t0[3]);
                sum += __shfl_xor(sum, 16);
                sum += __shfl_xor(sum, 32);
            }
            const float inv = 1.f / sum;

            // ---- P granules (registers only) ----
            bf16x4 pg[8];
#pragma unroll
            for (int nt = 0; nt < 8; ++nt)
                pg[nt] = pk4(s[nt][0] * inv, s[nt][1] * inv, s[nt][2] * inv, s[nt][3] * inv);

            // ---- O = P·V via mfma16: lane gets O[mt+c][d0+4g+r] ----
            f32x4 ot[4];
#pragma unroll
            for (int dt = 0; dt < 4; ++dt) ot[dt] = (f32x4)0.0f;
#pragma unroll
            for (int dt = 0; dt < 4; ++dt) {
                const int d0 = dt * 16;
#pragma unroll
                for (int nt = 0; nt < 8; ++nt) {
                    const bf16x4 vgr = *(const bf16x4*)&VTc[sw128(d0 + c, nt * 16 + 4 * g)];
                    ot[dt] = MFMA16(vgr, pg[nt], ot[dt]);
                }
            }

            // ---- out-proj accumulate straight from O granules ----
            bf16x4 ogr[4];
#pragma unroll
            for (int dt = 0; dt < 4; ++dt)
                ogr[dt] = pk4(ot[dt][0], ot[dt][1], ot[dt][2], ot[dt][3]);
#pragma unroll
            for (int nt4 = 0; nt4 < 4; ++nt4) {
                const int n0 = nt4 * 16;
#pragma unroll
                for (int dt = 0; dt < 4; ++dt) {
                    const bf16x4 wgr = *(const bf16x4*)&WpT[(n0 + c) * 512 + h * 64 + dt * 16 + 4 * g];
                    projacc[nt4] = MFMA16(ogr[dt], wgr, projacc[nt4]);
                }
            }
        } else if (h < NH - 1) {
            // ---- producers: next head's K/V^T into the other buffer ----
            PROJKV(h + 1, bufn);
        }

        __syncthreads();   // one barrier per head (uniform flow: outside the role ifs)
    }

    // ---- epilogue: consumers add bp and store ----
    if (cons) {
        float* og = out + (size_t)b * NM * ND;
#pragma unroll
        for (int nt4 = 0; nt4 < 4; ++nt4) {
            const int n0 = nt4 * 16;
            const float bpv = bp[n0 + c];
#pragma unroll
            for (int r = 0; r < 4; ++r)
                og[(mt + 4 * g + r) * ND + n0 + c] = projacc[nt4][r] + bpv;
        }
    }
}

extern "C" void kernel_launch(void* const* d_in, const int* in_sizes, int n_in,
                              void* d_out, int out_size, void* d_ws, size_t ws_size,
                              hipStream_t stream) {
    const float* x     = (const float*)d_in[0];
    const int*   edges = (const int*)d_in[1];
    const float* Wq    = (const float*)d_in[2];
    const float* bq    = (const float*)d_in[3];
    const float* Wk    = (const float*)d_in[4];
    const float* bk    = (const float*)d_in[5];
    const float* Wv    = (const float*)d_in[6];
    const float* bv    = (const float*)d_in[7];
    const float* eb    = (const float*)d_in[8];
    const float* Wp    = (const float*)d_in[9];
    const float* bp    = (const float*)d_in[10];
    float* out = (float*)d_out;
    ushort_t* ws = (ushort_t*)d_ws;   // needs 262144 B

    hipLaunchKernelGGL(geat_prep, dim3(512), dim3(256), 0, stream, Wq, Wk, Wv, Wp, ws);
    hipLaunchKernelGGL(geat_pc, dim3(NB), dim3(768), 0, stream,
                       x, edges, bq, bk, bv, eb, bp, ws, out);
}